// Round 6
// baseline (2469.230 us; speedup 1.0000x reference)
//
#include <hip/hip_runtime.h>

#define KITER 16
#define NBKT 512   // max buckets (bucket = 256 target nodes); n <= 131072

typedef __attribute__((ext_vector_type(8))) short short8;
typedef __attribute__((ext_vector_type(4))) float f32x4;

__device__ __forceinline__ unsigned short f2bf(float f) {
    unsigned int u = __float_as_uint(f);
    u = (u + 0x7fffu + ((u >> 16) & 1u)) >> 16;
    return (unsigned short)u;
}
__device__ __forceinline__ float bf2f(unsigned short h) {
    return __uint_as_float(((unsigned int)h) << 16);
}

// ---------------------------------------------------------------- init
__global__ void k_init(int* bktcnt, int* flag) {
    int i = blockIdx.x * blockDim.x + threadIdx.x;
    if (i < NBKT) bktcnt[i] = 0;
    if (i == 0) *flag = 1;
}

// Detect int64 vs int32 edge_index
__global__ void k_detect(const int* ew, int e, int* flag) {
    int t = blockIdx.x * blockDim.x + threadIdx.x;
    if (t < 512 && t < e) {
        if (ew[2 * t + 1] != 0) atomicAnd(flag, 0);
    }
}

// ---------------------------------------------------------------- bucket histogram (LDS-staged)
__global__ __launch_bounds__(256) void k_bhist(const void* eptr, int E, const int* flag,
        int* bktcnt, int n) {
    __shared__ int h[NBKT];
    const int NB = (n + 255) >> 8;
    for (int i = threadIdx.x; i < NB; i += 256) h[i] = 0;
    __syncthreads();
    const int tid0 = blockIdx.x * 256 + threadIdx.x;
    const int stride = gridDim.x * 256;
    if (*flag) {
        const long long* pc = (const long long*)eptr + E;
        for (int i = tid0; i < E; i += stride) atomicAdd(&h[((int)pc[i]) >> 8], 1);
    } else {
        const int* pc = (const int*)eptr + E;
        for (int i = tid0; i < E; i += stride) atomicAdd(&h[pc[i] >> 8], 1);
    }
    __syncthreads();
    for (int i = threadIdx.x; i < NB; i += 256) if (h[i]) atomicAdd(&bktcnt[i], h[i]);
}

// ---------------------------------------------------------------- scan bucket totals -> bases
__global__ __launch_bounds__(512) void k_bscan(const int* bktcnt, int* bktbase, int* bcur, int n) {
    __shared__ int s[NBKT];
    const int NB = (n + 255) >> 8;
    const int tid = threadIdx.x;
    int v = (tid < NB) ? bktcnt[tid] : 0;
    s[tid] = v;
    __syncthreads();
    for (int off = 1; off < NBKT; off <<= 1) {
        int t = (tid >= off) ? s[tid - off] : 0;
        __syncthreads();
        s[tid] += t;
        __syncthreads();
    }
    int excl = s[tid] - v;
    if (tid < NB) { bktbase[tid] = excl; bcur[tid] = excl; }
    if (tid == NB - 1) bktbase[NB] = s[tid];
}

// ---------------------------------------------------------------- phase A: bucket partition
// ebuf entry: (src << 8) | (c & 255)
__global__ __launch_bounds__(256) void k_bucketA(const void* eptr, int E, const int* flag,
        int* bcur, unsigned int* ebuf, int n) {
    __shared__ int hist[NBKT];
    __shared__ int lbase[NBKT];
    __shared__ int lcur[NBKT];
    const int NB = (n + 255) >> 8;
    const int wg = blockIdx.x, nwg = gridDim.x, tid = threadIdx.x;
    const int s0 = (int)(((long long)E * wg) / nwg);
    const int s1 = (int)(((long long)E * (wg + 1)) / nwg);
    for (int b = tid; b < NB; b += 256) { hist[b] = 0; lcur[b] = 0; }
    __syncthreads();
    const bool w64 = (*flag != 0);
    if (w64) {
        const long long* pc = (const long long*)eptr + E;
        for (int i = s0 + tid; i < s1; i += 256)
            atomicAdd(&hist[((int)pc[i]) >> 8], 1);
    } else {
        const int* pc = (const int*)eptr + E;
        for (int i = s0 + tid; i < s1; i += 256)
            atomicAdd(&hist[pc[i] >> 8], 1);
    }
    __syncthreads();
    for (int b = tid; b < NB; b += 256)
        lbase[b] = hist[b] ? atomicAdd(&bcur[b], hist[b]) : 0;
    __syncthreads();
    if (w64) {
        const long long* ps = (const long long*)eptr;
        const long long* pc = ps + E;
        for (int i = s0 + tid; i < s1; i += 256) {
            int c = (int)pc[i];
            int s = (int)ps[i];
            int b = c >> 8;
            int pos = lbase[b] + atomicAdd(&lcur[b], 1);
            ebuf[pos] = ((unsigned int)s << 8) | (unsigned int)(c & 255);
        }
    } else {
        const int* ps = (const int*)eptr;
        const int* pc = ps + E;
        for (int i = s0 + tid; i < s1; i += 256) {
            int c = pc[i];
            int s = ps[i];
            int b = c >> 8;
            int pos = lbase[b] + atomicAdd(&lcur[b], 1);
            ebuf[pos] = ((unsigned int)s << 8) | (unsigned int)(c & 255);
        }
    }
}

// ---------------------------------------------------------------- phase B: within-bucket CSR + rowptr + dinv
// rec stores src*32 (byte offset of the 32-B group row).
__global__ __launch_bounds__(256) void k_bucketB(const unsigned int* ebuf, const int* bktbase,
        int* rowptr, int* rec, float* dinv, int n) {
    __shared__ int cnt[256];
    __shared__ int base[256];
    __shared__ int cur[256];
    const int NB = (n + 255) >> 8;
    const int b = blockIdx.x;
    const int lo = b << 8;
    const int nloc = min(256, n - lo);
    const int tid = threadIdx.x;
    cnt[tid] = 0; cur[tid] = 0;
    __syncthreads();
    const int e0 = bktbase[b], e1 = bktbase[b + 1];
    for (int i = e0 + tid; i < e1; i += 256)
        atomicAdd(&cnt[ebuf[i] & 255u], 1);
    __syncthreads();
    int v = cnt[tid];
    base[tid] = v;
    __syncthreads();
    for (int off = 1; off < 256; off <<= 1) {
        int t = (tid >= off) ? base[tid - off] : 0;
        __syncthreads();
        base[tid] += t;
        __syncthreads();
    }
    int ebase = e0 + base[tid] - v;
    if (tid < nloc) {
        rowptr[lo + tid] = ebase;
        dinv[lo + tid] = 1.0f / sqrtf((float)(v + 1));
    }
    base[tid] = ebase;
    __syncthreads();
    if (b == 0 && tid == 0) rowptr[n] = bktbase[NB];
    for (int i = e0 + tid; i < e1; i += 256) {
        unsigned int q = ebuf[i];
        int cl = (int)(q & 255u);
        int pos = base[cl] + atomicAdd(&cur[cl], 1);
        rec[pos] = (int)((q >> 8) << 5);
    }
}

// ---------------------------------------------------------------- W1/W2 -> bf16 MFMA-fragment layout
__global__ void k_wprep(const float* __restrict__ W1, const float* __restrict__ W2,
                        unsigned short* __restrict__ W1f, unsigned short* __restrict__ W2f) {
    int t = blockIdx.x * 256 + threadIdx.x;
    if (t < 65536) {
        int e = t & 7, lane = (t >> 3) & 63, nf = (t >> 9) & 7, kt = t >> 12;
        int k = kt * 32 + 8 * (lane >> 4) + e;
        int nn = nf * 16 + (lane & 15);
        W1f[t] = f2bf(W1[k * 128 + nn]);
    } else if (t < 65536 + 8192) {
        int t2 = t - 65536;
        int e = t2 & 7, lane = (t2 >> 3) & 63, nf = (t2 >> 9) & 3, kt2 = t2 >> 11;
        int k = kt2 * 32 + 8 * (lane >> 4) + e;
        int nn = nf * 16 + (lane & 15);
        W2f[t2] = f2bf(W2[k * 64 + nn]);
    }
}

// ---------------------------------------------------------------- MFMA MLP: v = relu(x@W1+b1)@W2+b2
// Emits ax0g / zs0g in channel-group layout [g(4)][node][16].
__global__ __launch_bounds__(256) void k_mlp(const float* __restrict__ x,
        const unsigned short* __restrict__ W1f, const float* __restrict__ b1,
        const unsigned short* __restrict__ W2f, const float* __restrict__ b2,
        const float* __restrict__ dinv,
        unsigned short* __restrict__ ax0, unsigned short* __restrict__ zs0, int n) {
    __shared__ unsigned short Xs[4][64][8];
    __shared__ unsigned short HsP[4][64][40];   // padded 80-B rows: ~2-way banks max

    const int tid  = threadIdx.x;
    const int lane = tid & 63;
    const int wv   = tid >> 6;
    const int bm0  = blockIdx.x * 64;

    const int sr = tid >> 2;
    const int sk = tid & 3;
    const long long srow = (long long)bm0 + sr;
    const bool svalid = srow < n;
    const float* xp = x + srow * 512 + sk * 8;

    f32x4 acc[4][2];
#pragma unroll
    for (int mf = 0; mf < 4; ++mf)
#pragma unroll
        for (int nf = 0; nf < 2; ++nf) acc[mf][nf] = (f32x4){0.f, 0.f, 0.f, 0.f};

    for (int kt = 0; kt < 16; ++kt) {
        float4 f0 = {0, 0, 0, 0}, f1 = {0, 0, 0, 0};
        if (svalid) {
            f0 = *(const float4*)(xp + kt * 32);
            f1 = *(const float4*)(xp + kt * 32 + 4);
        }
        uint4 pk;
        pk.x = (unsigned int)f2bf(f0.x) | ((unsigned int)f2bf(f0.y) << 16);
        pk.y = (unsigned int)f2bf(f0.z) | ((unsigned int)f2bf(f0.w) << 16);
        pk.z = (unsigned int)f2bf(f1.x) | ((unsigned int)f2bf(f1.y) << 16);
        pk.w = (unsigned int)f2bf(f1.z) | ((unsigned int)f2bf(f1.w) << 16);
        *(uint4*)&Xs[sr >> 4][(sr & 15) + 16 * sk][0] = pk;
        __syncthreads();

        short8 bf[2];
#pragma unroll
        for (int nf = 0; nf < 2; ++nf)
            bf[nf] = *(const short8*)(W1f + (((size_t)kt * 8 + wv * 2 + nf) * 64 + lane) * 8);
#pragma unroll
        for (int mf = 0; mf < 4; ++mf) {
            short8 af = *(const short8*)&Xs[mf][lane][0];
#pragma unroll
            for (int nf = 0; nf < 2; ++nf)
                acc[mf][nf] = __builtin_amdgcn_mfma_f32_16x16x32_bf16(af, bf[nf], acc[mf][nf], 0, 0, 0);
        }
        __syncthreads();
    }

    // bias + relu -> HsP[wv][row][kk] (kk = k within this wave's 32-slice)
    const int c0 = wv * 32 + (lane & 15);
    const float b1v0 = b1[c0];
    const float b1v1 = b1[c0 + 16];
#pragma unroll
    for (int mf = 0; mf < 4; ++mf) {
#pragma unroll
        for (int nf = 0; nf < 2; ++nf) {
            float bb = nf ? b1v1 : b1v0;
            int kk = nf * 16 + (lane & 15);
#pragma unroll
            for (int r = 0; r < 4; ++r) {
                int row = mf * 16 + 4 * (lane >> 4) + r;
                float h = fmaxf(acc[mf][nf][r] + bb, 0.0f);
                HsP[wv][row][kk] = f2bf(h);
            }
        }
    }
    __syncthreads();

    f32x4 acc2[4];
#pragma unroll
    for (int mf = 0; mf < 4; ++mf) acc2[mf] = (f32x4){0.f, 0.f, 0.f, 0.f};
#pragma unroll
    for (int kt2 = 0; kt2 < 4; ++kt2) {
        short8 bf2 = *(const short8*)(W2f + (((size_t)kt2 * 4 + wv) * 64 + lane) * 8);
#pragma unroll
        for (int mf = 0; mf < 4; ++mf) {
            short8 af2 = *(const short8*)&HsP[kt2][mf * 16 + (lane & 15)][8 * (lane >> 4)];
            acc2[mf] = __builtin_amdgcn_mfma_f32_16x16x32_bf16(af2, bf2, acc2[mf], 0, 0, 0);
        }
    }

    // out channel oc = wv*16 + (lane&15) -> group wv, idx lane&15
    const int oc16 = lane & 15;
    const float bo = b2[wv * 16 + oc16];
    const size_t goff = (size_t)wv * n * 16;
#pragma unroll
    for (int mf = 0; mf < 4; ++mf) {
#pragma unroll
        for (int r = 0; r < 4; ++r) {
            long long row = (long long)bm0 + mf * 16 + 4 * (lane >> 4) + r;
            if (row < n) {
                float v = acc2[mf][r] + bo;
                ax0[goff + row * 16 + oc16] = f2bf(0.1f * v);
                zs0[goff + row * 16 + oc16] = f2bf(dinv[row] * v);
            }
        }
    }
}

// ---------------------------------------------------------------- propagation, channel-group x XCD partitioned
// zs layout [g(4)][node][16] bf16 (3.2 MB per group -> per-XCD L2 resident).
// blockIdx&7 = XCD (heuristic): group = xcd&3, node-half = xcd>>2.
// Wave = node; lanes = 4 edge-slots x 16 channels; rec holds src*32 byte offsets.
template<int LAST>
__global__ __launch_bounds__(256) void k_propg(const unsigned short* __restrict__ zs,
        const unsigned short* __restrict__ ax0, const int* __restrict__ rowptr,
        const int* __restrict__ rec, const float* __restrict__ dinv,
        unsigned short* __restrict__ zso, float* __restrict__ zfout,
        int n, int half, int jmax) {
    const int bid = blockIdx.x;
    const int xcd = bid & 7;
    const int j   = bid >> 3;
    const int g   = xcd & 3;
    const int h   = xcd >> 2;
    const int wv  = threadIdx.x >> 6;
    int node = h * half + j * 4 + wv;
    const int lim = h ? n : half;
    if (node >= lim) return;
    node = __builtin_amdgcn_readfirstlane(node);

    const int lane = threadIdx.x & 63;
    const int slot = lane >> 4;
    const int ch2  = (lane & 15) * 2;          // channel byte offset
    const char* zgb = (const char*)zs + (size_t)g * n * 32;
    const size_t nb16 = (size_t)node * 16 + (lane & 15);

    const int e0 = rowptr[node], e1 = rowptr[node + 1];
    float A0 = 0.f, A1 = 0.f, A2 = 0.f, A3 = 0.f;
    int e = e0 + slot;
    for (; e + 12 < e1; e += 16) {
        int r0 = rec[e];
        int r1 = rec[e + 4];
        int r2 = rec[e + 8];
        int r3 = rec[e + 12];
        A0 += bf2f(*(const unsigned short*)(zgb + (size_t)r0 + ch2));
        A1 += bf2f(*(const unsigned short*)(zgb + (size_t)r1 + ch2));
        A2 += bf2f(*(const unsigned short*)(zgb + (size_t)r2 + ch2));
        A3 += bf2f(*(const unsigned short*)(zgb + (size_t)r3 + ch2));
    }
    for (; e < e1; e += 4) {
        int r0 = rec[e];
        A0 += bf2f(*(const unsigned short*)(zgb + (size_t)r0 + ch2));
    }
    float acc = (A0 + A1) + (A2 + A3);
    acc += __shfl_xor(acc, 16, 64);
    acc += __shfl_xor(acc, 32, 64);
    acc += bf2f(((const unsigned short*)zgb)[nb16]);   // self loop, added once
    const float dv = dinv[node];
    const float zf = 0.9f * (dv * acc) + bf2f(ax0[(size_t)g * n * 16 + nb16]);
    if (slot == 0) {
        if (LAST) zfout[(size_t)node * 64 + g * 16 + (lane & 15)] = zf;
        else      zso[(size_t)g * n * 16 + nb16] = f2bf(dv * zf);
    }
}

// ---------------------------------------------------------------- log_softmax in place (row = wave)
__global__ __launch_bounds__(256) void k_lsm(float* z, int n) {
    int node = blockIdx.x * 4 + (threadIdx.x >> 6);
    if (node >= n) return;
    int lane = threadIdx.x & 63;
    long long base = ((long long)node << 6) + lane;
    float v = z[base];
    float m = v;
#pragma unroll
    for (int o = 32; o >= 1; o >>= 1) m = fmaxf(m, __shfl_xor(m, o, 64));
    float e = expf(v - m);
    float s = e;
#pragma unroll
    for (int o = 32; o >= 1; o >>= 1) s += __shfl_xor(s, o, 64);
    z[base] = v - m - logf(s);
}

// ---------------------------------------------------------------- launch
extern "C" void kernel_launch(void* const* d_in, const int* in_sizes, int n_in,
                              void* d_out, int out_size, void* d_ws, size_t ws_size,
                              hipStream_t stream) {
    const float* x  = (const float*)d_in[0];
    const void*  ei = d_in[1];
    const float* W1 = (const float*)d_in[2];
    const float* b1 = (const float*)d_in[3];
    const float* W2 = (const float*)d_in[4];
    const float* b2 = (const float*)d_in[5];
    float* out = (float*)d_out;

    const int n = in_sizes[0] / 512;
    const int E = in_sizes[1] / 2;
    const int NB = (n + 255) >> 8;

    char* p = (char*)d_ws;
    auto alloc = [&](size_t bytes) {
        void* r = (void*)p;
        p += (bytes + 255) & ~(size_t)255;
        return r;
    };
    int*   rowptr  = (int*)alloc((size_t)(n + 1) * 4);
    int*   flag    = (int*)alloc(4);
    int*   bktcnt  = (int*)alloc(NBKT * 4);
    int*   bktbase = (int*)alloc((NBKT + 1) * 4);
    int*   bcur    = (int*)alloc(NBKT * 4);
    float* dinv    = (float*)alloc((size_t)n * 4);
    int*   rec     = (int*)alloc((size_t)E * 4);
    unsigned int* ebuf = (unsigned int*)alloc((size_t)E * 4);
    unsigned short* ax0 = (unsigned short*)alloc((size_t)n * 64 * 2);
    unsigned short* zsA = (unsigned short*)alloc((size_t)n * 64 * 2);
    unsigned short* zsB = (unsigned short*)alloc((size_t)n * 64 * 2);
    unsigned short* W1f = (unsigned short*)alloc(65536 * 2);
    unsigned short* W2f = (unsigned short*)alloc(8192 * 2);

    k_init<<<2, 256, 0, stream>>>(bktcnt, flag);
    k_detect<<<2, 256, 0, stream>>>((const int*)ei, E, flag);
    k_wprep<<<(65536 + 8192 + 255) / 256, 256, 0, stream>>>(W1, W2, W1f, W2f);
    k_bhist<<<512, 256, 0, stream>>>(ei, E, flag, bktcnt, n);
    k_bscan<<<1, 512, 0, stream>>>(bktcnt, bktbase, bcur, n);
    k_bucketA<<<512, 256, 0, stream>>>(ei, E, flag, bcur, ebuf, n);
    k_bucketB<<<NB, 256, 0, stream>>>(ebuf, bktbase, rowptr, rec, dinv, n);
    k_mlp<<<(n + 63) / 64, 256, 0, stream>>>(x, W1f, b1, W2f, b2, dinv, ax0, zsA, n);

    const int half = (n + 1) / 2;
    const int jmax = (half + 3) / 4;
    const int grid = 8 * jmax;

    const unsigned short* zi = zsA;
    unsigned short* zo = zsB;
    for (int it = 0; it < KITER - 1; ++it) {
        k_propg<0><<<grid, 256, 0, stream>>>(zi, ax0, rowptr, rec, dinv, zo, nullptr, n, half, jmax);
        const unsigned short* t = zi; zi = zo; zo = (unsigned short*)t;
    }
    k_propg<1><<<grid, 256, 0, stream>>>(zi, ax0, rowptr, rec, dinv, nullptr, out, n, half, jmax);
    k_lsm<<<(n + 3) / 4, 256, 0, stream>>>(out, n);
}

// Round 7
// 1477.776 us; speedup vs baseline: 1.6709x; 1.6709x over previous
//
#include <hip/hip_runtime.h>

#define KITER 16
#define NBKT 512   // max buckets (bucket = 256 target nodes); n <= 131072

typedef __attribute__((ext_vector_type(8))) short short8;
typedef __attribute__((ext_vector_type(4))) float f32x4;

__device__ __forceinline__ unsigned short f2bf(float f) {
    unsigned int u = __float_as_uint(f);
    u = (u + 0x7fffu + ((u >> 16) & 1u)) >> 16;
    return (unsigned short)u;
}
__device__ __forceinline__ float bf2f(unsigned short h) {
    return __uint_as_float(((unsigned int)h) << 16);
}
__device__ __forceinline__ float ulo(unsigned int d) {   // low bf16 -> f32
    return __uint_as_float(d << 16);
}
__device__ __forceinline__ float uhi(unsigned int d) {   // high bf16 -> f32
    return __uint_as_float(d & 0xffff0000u);
}

// ---------------------------------------------------------------- init
__global__ void k_init(int* bktcnt, int* flag) {
    int i = blockIdx.x * blockDim.x + threadIdx.x;
    if (i < NBKT) bktcnt[i] = 0;
    if (i == 0) *flag = 1;
}

// Detect int64 vs int32 edge_index
__global__ void k_detect(const int* ew, int e, int* flag) {
    int t = blockIdx.x * blockDim.x + threadIdx.x;
    if (t < 512 && t < e) {
        if (ew[2 * t + 1] != 0) atomicAnd(flag, 0);
    }
}

// ---------------------------------------------------------------- bucket histogram (LDS-staged)
__global__ __launch_bounds__(256) void k_bhist(const void* eptr, int E, const int* flag,
        int* bktcnt, int n) {
    __shared__ int h[NBKT];
    const int NB = (n + 255) >> 8;
    for (int i = threadIdx.x; i < NB; i += 256) h[i] = 0;
    __syncthreads();
    const int tid0 = blockIdx.x * 256 + threadIdx.x;
    const int stride = gridDim.x * 256;
    if (*flag) {
        const long long* pc = (const long long*)eptr + E;
        for (int i = tid0; i < E; i += stride) atomicAdd(&h[((int)pc[i]) >> 8], 1);
    } else {
        const int* pc = (const int*)eptr + E;
        for (int i = tid0; i < E; i += stride) atomicAdd(&h[pc[i] >> 8], 1);
    }
    __syncthreads();
    for (int i = threadIdx.x; i < NB; i += 256) if (h[i]) atomicAdd(&bktcnt[i], h[i]);
}

// ---------------------------------------------------------------- scan bucket totals -> bases
__global__ __launch_bounds__(512) void k_bscan(const int* bktcnt, int* bktbase, int* bcur, int n) {
    __shared__ int s[NBKT];
    const int NB = (n + 255) >> 8;
    const int tid = threadIdx.x;
    int v = (tid < NB) ? bktcnt[tid] : 0;
    s[tid] = v;
    __syncthreads();
    for (int off = 1; off < NBKT; off <<= 1) {
        int t = (tid >= off) ? s[tid - off] : 0;
        __syncthreads();
        s[tid] += t;
        __syncthreads();
    }
    int excl = s[tid] - v;
    if (tid < NB) { bktbase[tid] = excl; bcur[tid] = excl; }
    if (tid == NB - 1) bktbase[NB] = s[tid];
}

// ---------------------------------------------------------------- phase A: bucket partition
// ebuf entry: (src << 8) | (c & 255)
__global__ __launch_bounds__(256) void k_bucketA(const void* eptr, int E, const int* flag,
        int* bcur, unsigned int* ebuf, int n) {
    __shared__ int hist[NBKT];
    __shared__ int lbase[NBKT];
    __shared__ int lcur[NBKT];
    const int NB = (n + 255) >> 8;
    const int wg = blockIdx.x, nwg = gridDim.x, tid = threadIdx.x;
    const int s0 = (int)(((long long)E * wg) / nwg);
    const int s1 = (int)(((long long)E * (wg + 1)) / nwg);
    for (int b = tid; b < NB; b += 256) { hist[b] = 0; lcur[b] = 0; }
    __syncthreads();
    const bool w64 = (*flag != 0);
    if (w64) {
        const long long* pc = (const long long*)eptr + E;
        for (int i = s0 + tid; i < s1; i += 256)
            atomicAdd(&hist[((int)pc[i]) >> 8], 1);
    } else {
        const int* pc = (const int*)eptr + E;
        for (int i = s0 + tid; i < s1; i += 256)
            atomicAdd(&hist[pc[i] >> 8], 1);
    }
    __syncthreads();
    for (int b = tid; b < NB; b += 256)
        lbase[b] = hist[b] ? atomicAdd(&bcur[b], hist[b]) : 0;
    __syncthreads();
    if (w64) {
        const long long* ps = (const long long*)eptr;
        const long long* pc = ps + E;
        for (int i = s0 + tid; i < s1; i += 256) {
            int c = (int)pc[i];
            int s = (int)ps[i];
            int b = c >> 8;
            int pos = lbase[b] + atomicAdd(&lcur[b], 1);
            ebuf[pos] = ((unsigned int)s << 8) | (unsigned int)(c & 255);
        }
    } else {
        const int* ps = (const int*)eptr;
        const int* pc = ps + E;
        for (int i = s0 + tid; i < s1; i += 256) {
            int c = pc[i];
            int s = ps[i];
            int b = c >> 8;
            int pos = lbase[b] + atomicAdd(&lcur[b], 1);
            ebuf[pos] = ((unsigned int)s << 8) | (unsigned int)(c & 255);
        }
    }
}

// ---------------------------------------------------------------- phase B: within-bucket CSR + rowptr + dinv
// rec stores src*128 (byte offset of a [node][64] bf16 row).
__global__ __launch_bounds__(256) void k_bucketB(const unsigned int* ebuf, const int* bktbase,
        int* rowptr, int* rec, float* dinv, int n) {
    __shared__ int cnt[256];
    __shared__ int base[256];
    __shared__ int cur[256];
    const int NB = (n + 255) >> 8;
    const int b = blockIdx.x;
    const int lo = b << 8;
    const int nloc = min(256, n - lo);
    const int tid = threadIdx.x;
    cnt[tid] = 0; cur[tid] = 0;
    __syncthreads();
    const int e0 = bktbase[b], e1 = bktbase[b + 1];
    for (int i = e0 + tid; i < e1; i += 256)
        atomicAdd(&cnt[ebuf[i] & 255u], 1);
    __syncthreads();
    int v = cnt[tid];
    base[tid] = v;
    __syncthreads();
    for (int off = 1; off < 256; off <<= 1) {
        int t = (tid >= off) ? base[tid - off] : 0;
        __syncthreads();
        base[tid] += t;
        __syncthreads();
    }
    int ebase = e0 + base[tid] - v;
    if (tid < nloc) {
        rowptr[lo + tid] = ebase;
        dinv[lo + tid] = 1.0f / sqrtf((float)(v + 1));
    }
    base[tid] = ebase;
    __syncthreads();
    if (b == 0 && tid == 0) rowptr[n] = bktbase[NB];
    for (int i = e0 + tid; i < e1; i += 256) {
        unsigned int q = ebuf[i];
        int cl = (int)(q & 255u);
        int pos = base[cl] + atomicAdd(&cur[cl], 1);
        rec[pos] = (int)((q >> 8) << 7);   // src * 128 bytes
    }
}

// ---------------------------------------------------------------- W1/W2 -> bf16 MFMA-fragment layout
__global__ void k_wprep(const float* __restrict__ W1, const float* __restrict__ W2,
                        unsigned short* __restrict__ W1f, unsigned short* __restrict__ W2f) {
    int t = blockIdx.x * 256 + threadIdx.x;
    if (t < 65536) {
        int e = t & 7, lane = (t >> 3) & 63, nf = (t >> 9) & 7, kt = t >> 12;
        int k = kt * 32 + 8 * (lane >> 4) + e;
        int nn = nf * 16 + (lane & 15);
        W1f[t] = f2bf(W1[k * 128 + nn]);
    } else if (t < 65536 + 8192) {
        int t2 = t - 65536;
        int e = t2 & 7, lane = (t2 >> 3) & 63, nf = (t2 >> 9) & 3, kt2 = t2 >> 11;
        int k = kt2 * 32 + 8 * (lane >> 4) + e;
        int nn = nf * 16 + (lane & 15);
        W2f[t2] = f2bf(W2[k * 64 + nn]);
    }
}

// ---------------------------------------------------------------- MFMA MLP: v = relu(x@W1+b1)@W2+b2
// Double-buffered X staging (1 barrier/iter); emits ax0 = bf16(0.1*v),
// zs0 = bf16(dinv*v), both [node][64].
__global__ __launch_bounds__(256) void k_mlp(const float* __restrict__ x,
        const unsigned short* __restrict__ W1f, const float* __restrict__ b1,
        const unsigned short* __restrict__ W2f, const float* __restrict__ b2,
        const float* __restrict__ dinv,
        unsigned short* __restrict__ ax0, unsigned short* __restrict__ zs0, int n) {
    __shared__ union {
        unsigned short Xs[2][4][64][8];   // 8 KB  (A-frags, double-buffered)
        unsigned short HsP[4][64][40];    // 20 KB (h, padded 80-B rows)
    } sm;

    const int tid  = threadIdx.x;
    const int lane = tid & 63;
    const int wv   = tid >> 6;
    const int bm0  = blockIdx.x * 64;

    const int sr = tid >> 2;
    const int sk = tid & 3;
    const long long srow = (long long)bm0 + sr;
    const bool svalid = srow < n;
    const float* xp = x + srow * 512 + sk * 8;

    f32x4 acc[4][2];
#pragma unroll
    for (int mf = 0; mf < 4; ++mf)
#pragma unroll
        for (int nf = 0; nf < 2; ++nf) acc[mf][nf] = (f32x4){0.f, 0.f, 0.f, 0.f};

    // prologue: stage kt=0
    {
        float4 f0 = {0, 0, 0, 0}, f1 = {0, 0, 0, 0};
        if (svalid) { f0 = *(const float4*)(xp); f1 = *(const float4*)(xp + 4); }
        uint4 pk;
        pk.x = (unsigned int)f2bf(f0.x) | ((unsigned int)f2bf(f0.y) << 16);
        pk.y = (unsigned int)f2bf(f0.z) | ((unsigned int)f2bf(f0.w) << 16);
        pk.z = (unsigned int)f2bf(f1.x) | ((unsigned int)f2bf(f1.y) << 16);
        pk.w = (unsigned int)f2bf(f1.z) | ((unsigned int)f2bf(f1.w) << 16);
        *(uint4*)&sm.Xs[0][sr >> 4][(sr & 15) + 16 * sk][0] = pk;
    }
    __syncthreads();

    for (int kt = 0; kt < 16; ++kt) {
        // issue next tile's loads early (hidden under MFMAs)
        float4 g0 = {0, 0, 0, 0}, g1 = {0, 0, 0, 0};
        if (kt < 15 && svalid) {
            g0 = *(const float4*)(xp + (kt + 1) * 32);
            g1 = *(const float4*)(xp + (kt + 1) * 32 + 4);
        }

        short8 bf[2];
#pragma unroll
        for (int nf = 0; nf < 2; ++nf)
            bf[nf] = *(const short8*)(W1f + (((size_t)kt * 8 + wv * 2 + nf) * 64 + lane) * 8);
#pragma unroll
        for (int mf = 0; mf < 4; ++mf) {
            short8 af = *(const short8*)&sm.Xs[kt & 1][mf][lane][0];
#pragma unroll
            for (int nf = 0; nf < 2; ++nf)
                acc[mf][nf] = __builtin_amdgcn_mfma_f32_16x16x32_bf16(af, bf[nf], acc[mf][nf], 0, 0, 0);
        }

        if (kt < 15) {
            uint4 pk;
            pk.x = (unsigned int)f2bf(g0.x) | ((unsigned int)f2bf(g0.y) << 16);
            pk.y = (unsigned int)f2bf(g0.z) | ((unsigned int)f2bf(g0.w) << 16);
            pk.z = (unsigned int)f2bf(g1.x) | ((unsigned int)f2bf(g1.y) << 16);
            pk.w = (unsigned int)f2bf(g1.z) | ((unsigned int)f2bf(g1.w) << 16);
            *(uint4*)&sm.Xs[(kt + 1) & 1][sr >> 4][(sr & 15) + 16 * sk][0] = pk;
        }
        __syncthreads();
    }

    // bias + relu -> HsP[wv][row][kk]
    const int c0 = wv * 32 + (lane & 15);
    const float b1v0 = b1[c0];
    const float b1v1 = b1[c0 + 16];
#pragma unroll
    for (int mf = 0; mf < 4; ++mf) {
#pragma unroll
        for (int nf = 0; nf < 2; ++nf) {
            float bb = nf ? b1v1 : b1v0;
            int kk = nf * 16 + (lane & 15);
#pragma unroll
            for (int r = 0; r < 4; ++r) {
                int row = mf * 16 + 4 * (lane >> 4) + r;
                float h = fmaxf(acc[mf][nf][r] + bb, 0.0f);
                sm.HsP[wv][row][kk] = f2bf(h);
            }
        }
    }
    __syncthreads();

    f32x4 acc2[4];
#pragma unroll
    for (int mf = 0; mf < 4; ++mf) acc2[mf] = (f32x4){0.f, 0.f, 0.f, 0.f};
#pragma unroll
    for (int kt2 = 0; kt2 < 4; ++kt2) {
        short8 bf2 = *(const short8*)(W2f + (((size_t)kt2 * 4 + wv) * 64 + lane) * 8);
#pragma unroll
        for (int mf = 0; mf < 4; ++mf) {
            short8 af2 = *(const short8*)&sm.HsP[kt2][mf * 16 + (lane & 15)][8 * (lane >> 4)];
            acc2[mf] = __builtin_amdgcn_mfma_f32_16x16x32_bf16(af2, bf2, acc2[mf], 0, 0, 0);
        }
    }

    const int oc = wv * 16 + (lane & 15);
    const float bo = b2[oc];
#pragma unroll
    for (int mf = 0; mf < 4; ++mf) {
#pragma unroll
        for (int r = 0; r < 4; ++r) {
            long long row = (long long)bm0 + mf * 16 + 4 * (lane >> 4) + r;
            if (row < n) {
                float v = acc2[mf][r] + bo;
                ax0[row * 64 + oc] = f2bf(0.1f * v);
                zs0[row * 64 + oc] = f2bf(dinv[row] * v);
            }
        }
    }
}

// ---------------------------------------------------------------- propagation
// zs = bf16(dinv*z), layout [node][64]. Wave = node; lane covers channel pair
// c2 = lane&31 (dword loads); 2 edge-slots (lane>>5); 8 chains x 2 slots =
// 16 edges in flight; rec loads stay scalar (uniform e, slot via cndmask).
// LAST=1 fuses log_softmax, writes fp32 out.
template<int LAST>
__global__ __launch_bounds__(256) void k_prop(const unsigned short* __restrict__ zs,
        const unsigned short* __restrict__ ax0, const int* __restrict__ rowptr,
        const int* __restrict__ rec, const float* __restrict__ dinv,
        unsigned short* __restrict__ zso, float* __restrict__ zfout, int n) {
    int node = __builtin_amdgcn_readfirstlane(blockIdx.x * 4 + (threadIdx.x >> 6));
    if (node >= n) return;
    const int lane = threadIdx.x & 63;
    const int c2   = lane & 31;
    const int slot = lane >> 5;
    const int cb   = c2 * 4;
    const char* zb = (const char*)zs;
    const int e0 = rowptr[node], e1 = rowptr[node + 1];

    float a0x = 0.f, a0y = 0.f, a1x = 0.f, a1y = 0.f;
    float a2x = 0.f, a2y = 0.f, a3x = 0.f, a3y = 0.f;
    float a4x = 0.f, a4y = 0.f, a5x = 0.f, a5y = 0.f;
    float a6x = 0.f, a6y = 0.f, a7x = 0.f, a7y = 0.f;

    int e = e0;
    for (; e + 16 <= e1; e += 16) {
        int r0 = slot ? rec[e + 1]  : rec[e];
        int r1 = slot ? rec[e + 3]  : rec[e + 2];
        int r2 = slot ? rec[e + 5]  : rec[e + 4];
        int r3 = slot ? rec[e + 7]  : rec[e + 6];
        int r4 = slot ? rec[e + 9]  : rec[e + 8];
        int r5 = slot ? rec[e + 11] : rec[e + 10];
        int r6 = slot ? rec[e + 13] : rec[e + 12];
        int r7 = slot ? rec[e + 15] : rec[e + 14];
        unsigned int d0 = *(const unsigned int*)(zb + (size_t)r0 + cb);
        unsigned int d1 = *(const unsigned int*)(zb + (size_t)r1 + cb);
        unsigned int d2 = *(const unsigned int*)(zb + (size_t)r2 + cb);
        unsigned int d3 = *(const unsigned int*)(zb + (size_t)r3 + cb);
        unsigned int d4 = *(const unsigned int*)(zb + (size_t)r4 + cb);
        unsigned int d5 = *(const unsigned int*)(zb + (size_t)r5 + cb);
        unsigned int d6 = *(const unsigned int*)(zb + (size_t)r6 + cb);
        unsigned int d7 = *(const unsigned int*)(zb + (size_t)r7 + cb);
        a0x += ulo(d0); a0y += uhi(d0);
        a1x += ulo(d1); a1y += uhi(d1);
        a2x += ulo(d2); a2y += uhi(d2);
        a3x += ulo(d3); a3y += uhi(d3);
        a4x += ulo(d4); a4y += uhi(d4);
        a5x += ulo(d5); a5y += uhi(d5);
        a6x += ulo(d6); a6y += uhi(d6);
        a7x += ulo(d7); a7y += uhi(d7);
    }
    for (; e + 2 <= e1; e += 2) {
        int r = slot ? rec[e + 1] : rec[e];
        unsigned int d = *(const unsigned int*)(zb + (size_t)r + cb);
        a0x += ulo(d); a0y += uhi(d);
    }
    if (e < e1) {                      // odd leftover: slot 0 only
        int r = rec[e];
        unsigned int d = *(const unsigned int*)(zb + (size_t)r + cb);
        float w = slot ? 0.f : 1.f;
        a0x = fmaf(w, ulo(d), a0x);
        a0y = fmaf(w, uhi(d), a0y);
    }
    float sx = ((a0x + a1x) + (a2x + a3x)) + ((a4x + a5x) + (a6x + a7x));
    float sy = ((a0y + a1y) + (a2y + a3y)) + ((a4y + a5y) + (a6y + a7y));
    sx += __shfl_xor(sx, 32, 64);
    sy += __shfl_xor(sy, 32, 64);
    unsigned int ds = *(const unsigned int*)(zb + (size_t)node * 128 + cb);   // self loop
    sx += ulo(ds); sy += uhi(ds);
    const float dv = dinv[node];
    unsigned int da = *(const unsigned int*)((const char*)ax0 + (size_t)node * 128 + cb);
    float zx = 0.9f * (dv * sx) + ulo(da);
    float zy = 0.9f * (dv * sy) + uhi(da);
    if (LAST) {
        float m = fmaxf(zx, zy);
#pragma unroll
        for (int o = 16; o >= 1; o >>= 1) m = fmaxf(m, __shfl_xor(m, o, 64));
        float s = expf(zx - m) + expf(zy - m);
#pragma unroll
        for (int o = 16; o >= 1; o >>= 1) s += __shfl_xor(s, o, 64);
        float ls = logf(s);
        if (slot == 0) {
            float2 o2; o2.x = zx - m - ls; o2.y = zy - m - ls;
            *(float2*)(zfout + (size_t)node * 64 + c2 * 2) = o2;
        }
    } else {
        if (slot == 0) {
            unsigned int pk = (unsigned int)f2bf(dv * zx) | ((unsigned int)f2bf(dv * zy) << 16);
            *(unsigned int*)((char*)zso + (size_t)node * 128 + cb) = pk;
        }
    }
}

// ---------------------------------------------------------------- launch
extern "C" void kernel_launch(void* const* d_in, const int* in_sizes, int n_in,
                              void* d_out, int out_size, void* d_ws, size_t ws_size,
                              hipStream_t stream) {
    const float* x  = (const float*)d_in[0];
    const void*  ei = d_in[1];
    const float* W1 = (const float*)d_in[2];
    const float* b1 = (const float*)d_in[3];
    const float* W2 = (const float*)d_in[4];
    const float* b2 = (const float*)d_in[5];
    float* out = (float*)d_out;

    const int n = in_sizes[0] / 512;
    const int E = in_sizes[1] / 2;
    const int NB = (n + 255) >> 8;

    char* p = (char*)d_ws;
    auto alloc = [&](size_t bytes) {
        void* r = (void*)p;
        p += (bytes + 255) & ~(size_t)255;
        return r;
    };
    int*   rowptr  = (int*)alloc((size_t)(n + 1) * 4);
    int*   flag    = (int*)alloc(4);
    int*   bktcnt  = (int*)alloc(NBKT * 4);
    int*   bktbase = (int*)alloc((NBKT + 1) * 4);
    int*   bcur    = (int*)alloc(NBKT * 4);
    float* dinv    = (float*)alloc((size_t)n * 4);
    int*   rec     = (int*)alloc((size_t)E * 4);
    unsigned int* ebuf = (unsigned int*)alloc((size_t)E * 4);
    unsigned short* ax0 = (unsigned short*)alloc((size_t)n * 64 * 2);
    unsigned short* zsA = (unsigned short*)alloc((size_t)n * 64 * 2);
    unsigned short* zsB = (unsigned short*)alloc((size_t)n * 64 * 2);
    unsigned short* W1f = (unsigned short*)alloc(65536 * 2);
    unsigned short* W2f = (unsigned short*)alloc(8192 * 2);

    k_init<<<2, 256, 0, stream>>>(bktcnt, flag);
    k_detect<<<2, 256, 0, stream>>>((const int*)ei, E, flag);
    k_wprep<<<(65536 + 8192 + 255) / 256, 256, 0, stream>>>(W1, W2, W1f, W2f);
    k_bhist<<<512, 256, 0, stream>>>(ei, E, flag, bktcnt, n);
    k_bscan<<<1, 512, 0, stream>>>(bktcnt, bktbase, bcur, n);
    k_bucketA<<<512, 256, 0, stream>>>(ei, E, flag, bcur, ebuf, n);
    k_bucketB<<<NB, 256, 0, stream>>>(ebuf, bktbase, rowptr, rec, dinv, n);
    k_mlp<<<(n + 63) / 64, 256, 0, stream>>>(x, W1f, b1, W2f, b2, dinv, ax0, zsA, n);

    const unsigned short* zi = zsA;
    unsigned short* zo = zsB;
    for (int it = 0; it < KITER - 1; ++it) {
        k_prop<0><<<(n + 3) / 4, 256, 0, stream>>>(zi, ax0, rowptr, rec, dinv, zo, nullptr, n);
        const unsigned short* t = zi; zi = zo; zo = (unsigned short*)t;
    }
    k_prop<1><<<(n + 3) / 4, 256, 0, stream>>>(zi, ax0, rowptr, rec, dinv, nullptr, out, n);
}

// Round 8
// 1230.294 us; speedup vs baseline: 2.0070x; 1.2012x over previous
//
#include <hip/hip_runtime.h>

#define KITER 16
#define NBKT 512   // max buckets (bucket = 256 target nodes); n <= 131072

typedef __attribute__((ext_vector_type(8))) short short8;
typedef __attribute__((ext_vector_type(4))) float f32x4;

__device__ __forceinline__ unsigned short f2bf(float f) {
    unsigned int u = __float_as_uint(f);
    u = (u + 0x7fffu + ((u >> 16) & 1u)) >> 16;
    return (unsigned short)u;
}
__device__ __forceinline__ float bf2f(unsigned short h) {
    return __uint_as_float(((unsigned int)h) << 16);
}
__device__ __forceinline__ float ulo(unsigned int d) {   // low bf16 -> f32
    return __uint_as_float(d << 16);
}
__device__ __forceinline__ float uhi(unsigned int d) {   // high bf16 -> f32
    return __uint_as_float(d & 0xffff0000u);
}

// ---------------------------------------------------------------- init
__global__ void k_init(int* bktcnt, int* flag) {
    int i = blockIdx.x * blockDim.x + threadIdx.x;
    if (i < NBKT) bktcnt[i] = 0;
    if (i == 0) *flag = 1;
}

// Detect int64 vs int32 edge_index
__global__ void k_detect(const int* ew, int e, int* flag) {
    int t = blockIdx.x * blockDim.x + threadIdx.x;
    if (t < 512 && t < e) {
        if (ew[2 * t + 1] != 0) atomicAnd(flag, 0);
    }
}

// ---------------------------------------------------------------- bucket histogram (LDS-staged)
__global__ __launch_bounds__(256) void k_bhist(const void* eptr, int E, const int* flag,
        int* bktcnt, int n) {
    __shared__ int h[NBKT];
    const int NB = (n + 255) >> 8;
    for (int i = threadIdx.x; i < NB; i += 256) h[i] = 0;
    __syncthreads();
    const int tid0 = blockIdx.x * 256 + threadIdx.x;
    const int stride = gridDim.x * 256;
    if (*flag) {
        const long long* pc = (const long long*)eptr + E;
        for (int i = tid0; i < E; i += stride) atomicAdd(&h[((int)pc[i]) >> 8], 1);
    } else {
        const int* pc = (const int*)eptr + E;
        for (int i = tid0; i < E; i += stride) atomicAdd(&h[pc[i] >> 8], 1);
    }
    __syncthreads();
    for (int i = threadIdx.x; i < NB; i += 256) if (h[i]) atomicAdd(&bktcnt[i], h[i]);
}

// ---------------------------------------------------------------- scan bucket totals -> bases
__global__ __launch_bounds__(512) void k_bscan(const int* bktcnt, int* bktbase, int* bcur, int n) {
    __shared__ int s[NBKT];
    const int NB = (n + 255) >> 8;
    const int tid = threadIdx.x;
    int v = (tid < NB) ? bktcnt[tid] : 0;
    s[tid] = v;
    __syncthreads();
    for (int off = 1; off < NBKT; off <<= 1) {
        int t = (tid >= off) ? s[tid - off] : 0;
        __syncthreads();
        s[tid] += t;
        __syncthreads();
    }
    int excl = s[tid] - v;
    if (tid < NB) { bktbase[tid] = excl; bcur[tid] = excl; }
    if (tid == NB - 1) bktbase[NB] = s[tid];
}

// ---------------------------------------------------------------- phase A: bucket partition
// ebuf entry: (src << 8) | (c & 255)
__global__ __launch_bounds__(256) void k_bucketA(const void* eptr, int E, const int* flag,
        int* bcur, unsigned int* ebuf, int n) {
    __shared__ int hist[NBKT];
    __shared__ int lbase[NBKT];
    __shared__ int lcur[NBKT];
    const int NB = (n + 255) >> 8;
    const int wg = blockIdx.x, nwg = gridDim.x, tid = threadIdx.x;
    const int s0 = (int)(((long long)E * wg) / nwg);
    const int s1 = (int)(((long long)E * (wg + 1)) / nwg);
    for (int b = tid; b < NB; b += 256) { hist[b] = 0; lcur[b] = 0; }
    __syncthreads();
    const bool w64 = (*flag != 0);
    if (w64) {
        const long long* pc = (const long long*)eptr + E;
        for (int i = s0 + tid; i < s1; i += 256)
            atomicAdd(&hist[((int)pc[i]) >> 8], 1);
    } else {
        const int* pc = (const int*)eptr + E;
        for (int i = s0 + tid; i < s1; i += 256)
            atomicAdd(&hist[pc[i] >> 8], 1);
    }
    __syncthreads();
    for (int b = tid; b < NB; b += 256)
        lbase[b] = hist[b] ? atomicAdd(&bcur[b], hist[b]) : 0;
    __syncthreads();
    if (w64) {
        const long long* ps = (const long long*)eptr;
        const long long* pc = ps + E;
        for (int i = s0 + tid; i < s1; i += 256) {
            int c = (int)pc[i];
            int s = (int)ps[i];
            int b = c >> 8;
            int pos = lbase[b] + atomicAdd(&lcur[b], 1);
            ebuf[pos] = ((unsigned int)s << 8) | (unsigned int)(c & 255);
        }
    } else {
        const int* ps = (const int*)eptr;
        const int* pc = ps + E;
        for (int i = s0 + tid; i < s1; i += 256) {
            int c = pc[i];
            int s = ps[i];
            int b = c >> 8;
            int pos = lbase[b] + atomicAdd(&lcur[b], 1);
            ebuf[pos] = ((unsigned int)s << 8) | (unsigned int)(c & 255);
        }
    }
}

// ---------------------------------------------------------------- phase B: within-bucket CSR + rowptr + dinv
// rec stores src*128 (byte offset of a [node][64] bf16 row).
__global__ __launch_bounds__(256) void k_bucketB(const unsigned int* ebuf, const int* bktbase,
        int* rowptr, int* rec, float* dinv, int n) {
    __shared__ int cnt[256];
    __shared__ int base[256];
    __shared__ int cur[256];
    const int NB = (n + 255) >> 8;
    const int b = blockIdx.x;
    const int lo = b << 8;
    const int nloc = min(256, n - lo);
    const int tid = threadIdx.x;
    cnt[tid] = 0; cur[tid] = 0;
    __syncthreads();
    const int e0 = bktbase[b], e1 = bktbase[b + 1];
    for (int i = e0 + tid; i < e1; i += 256)
        atomicAdd(&cnt[ebuf[i] & 255u], 1);
    __syncthreads();
    int v = cnt[tid];
    base[tid] = v;
    __syncthreads();
    for (int off = 1; off < 256; off <<= 1) {
        int t = (tid >= off) ? base[tid - off] : 0;
        __syncthreads();
        base[tid] += t;
        __syncthreads();
    }
    int ebase = e0 + base[tid] - v;
    if (tid < nloc) {
        rowptr[lo + tid] = ebase;
        dinv[lo + tid] = 1.0f / sqrtf((float)(v + 1));
    }
    base[tid] = ebase;
    __syncthreads();
    if (b == 0 && tid == 0) rowptr[n] = bktbase[NB];
    for (int i = e0 + tid; i < e1; i += 256) {
        unsigned int q = ebuf[i];
        int cl = (int)(q & 255u);
        int pos = base[cl] + atomicAdd(&cur[cl], 1);
        rec[pos] = (int)((q >> 8) << 7);   // src * 128 bytes
    }
}

// ---------------------------------------------------------------- W1/W2 -> bf16 MFMA-fragment layout
__global__ void k_wprep(const float* __restrict__ W1, const float* __restrict__ W2,
                        unsigned short* __restrict__ W1f, unsigned short* __restrict__ W2f) {
    int t = blockIdx.x * 256 + threadIdx.x;
    if (t < 65536) {
        int e = t & 7, lane = (t >> 3) & 63, nf = (t >> 9) & 7, kt = t >> 12;
        int k = kt * 32 + 8 * (lane >> 4) + e;
        int nn = nf * 16 + (lane & 15);
        W1f[t] = f2bf(W1[k * 128 + nn]);
    } else if (t < 65536 + 8192) {
        int t2 = t - 65536;
        int e = t2 & 7, lane = (t2 >> 3) & 63, nf = (t2 >> 9) & 3, kt2 = t2 >> 11;
        int k = kt2 * 32 + 8 * (lane >> 4) + e;
        int nn = nf * 16 + (lane & 15);
        W2f[t2] = f2bf(W2[k * 64 + nn]);
    }
}

// ---------------------------------------------------------------- MFMA MLP: v = relu(x@W1+b1)@W2+b2
// Double-buffered X staging; emits ax0 = bf16(0.1*v), zs0 = bf16(dinv*v).
__global__ __launch_bounds__(256) void k_mlp(const float* __restrict__ x,
        const unsigned short* __restrict__ W1f, const float* __restrict__ b1,
        const unsigned short* __restrict__ W2f, const float* __restrict__ b2,
        const float* __restrict__ dinv,
        unsigned short* __restrict__ ax0, unsigned short* __restrict__ zs0, int n) {
    __shared__ union {
        unsigned short Xs[2][4][64][8];   // 8 KB  (A-frags, double-buffered)
        unsigned short HsP[4][64][40];    // 20 KB (h, padded 80-B rows)
    } sm;

    const int tid  = threadIdx.x;
    const int lane = tid & 63;
    const int wv   = tid >> 6;
    const int bm0  = blockIdx.x * 64;

    const int sr = tid >> 2;
    const int sk = tid & 3;
    const long long srow = (long long)bm0 + sr;
    const bool svalid = srow < n;
    const float* xp = x + srow * 512 + sk * 8;

    f32x4 acc[4][2];
#pragma unroll
    for (int mf = 0; mf < 4; ++mf)
#pragma unroll
        for (int nf = 0; nf < 2; ++nf) acc[mf][nf] = (f32x4){0.f, 0.f, 0.f, 0.f};

    {
        float4 f0 = {0, 0, 0, 0}, f1 = {0, 0, 0, 0};
        if (svalid) { f0 = *(const float4*)(xp); f1 = *(const float4*)(xp + 4); }
        uint4 pk;
        pk.x = (unsigned int)f2bf(f0.x) | ((unsigned int)f2bf(f0.y) << 16);
        pk.y = (unsigned int)f2bf(f0.z) | ((unsigned int)f2bf(f0.w) << 16);
        pk.z = (unsigned int)f2bf(f1.x) | ((unsigned int)f2bf(f1.y) << 16);
        pk.w = (unsigned int)f2bf(f1.z) | ((unsigned int)f2bf(f1.w) << 16);
        *(uint4*)&sm.Xs[0][sr >> 4][(sr & 15) + 16 * sk][0] = pk;
    }
    __syncthreads();

    for (int kt = 0; kt < 16; ++kt) {
        float4 g0 = {0, 0, 0, 0}, g1 = {0, 0, 0, 0};
        if (kt < 15 && svalid) {
            g0 = *(const float4*)(xp + (kt + 1) * 32);
            g1 = *(const float4*)(xp + (kt + 1) * 32 + 4);
        }

        short8 bf[2];
#pragma unroll
        for (int nf = 0; nf < 2; ++nf)
            bf[nf] = *(const short8*)(W1f + (((size_t)kt * 8 + wv * 2 + nf) * 64 + lane) * 8);
#pragma unroll
        for (int mf = 0; mf < 4; ++mf) {
            short8 af = *(const short8*)&sm.Xs[kt & 1][mf][lane][0];
#pragma unroll
            for (int nf = 0; nf < 2; ++nf)
                acc[mf][nf] = __builtin_amdgcn_mfma_f32_16x16x32_bf16(af, bf[nf], acc[mf][nf], 0, 0, 0);
        }

        if (kt < 15) {
            uint4 pk;
            pk.x = (unsigned int)f2bf(g0.x) | ((unsigned int)f2bf(g0.y) << 16);
            pk.y = (unsigned int)f2bf(g0.z) | ((unsigned int)f2bf(g0.w) << 16);
            pk.z = (unsigned int)f2bf(g1.x) | ((unsigned int)f2bf(g1.y) << 16);
            pk.w = (unsigned int)f2bf(g1.z) | ((unsigned int)f2bf(g1.w) << 16);
            *(uint4*)&sm.Xs[(kt + 1) & 1][sr >> 4][(sr & 15) + 16 * sk][0] = pk;
        }
        __syncthreads();
    }

    const int c0 = wv * 32 + (lane & 15);
    const float b1v0 = b1[c0];
    const float b1v1 = b1[c0 + 16];
#pragma unroll
    for (int mf = 0; mf < 4; ++mf) {
#pragma unroll
        for (int nf = 0; nf < 2; ++nf) {
            float bb = nf ? b1v1 : b1v0;
            int kk = nf * 16 + (lane & 15);
#pragma unroll
            for (int r = 0; r < 4; ++r) {
                int row = mf * 16 + 4 * (lane >> 4) + r;
                float h = fmaxf(acc[mf][nf][r] + bb, 0.0f);
                sm.HsP[wv][row][kk] = f2bf(h);
            }
        }
    }
    __syncthreads();

    f32x4 acc2[4];
#pragma unroll
    for (int mf = 0; mf < 4; ++mf) acc2[mf] = (f32x4){0.f, 0.f, 0.f, 0.f};
#pragma unroll
    for (int kt2 = 0; kt2 < 4; ++kt2) {
        short8 bf2 = *(const short8*)(W2f + (((size_t)kt2 * 4 + wv) * 64 + lane) * 8);
#pragma unroll
        for (int mf = 0; mf < 4; ++mf) {
            short8 af2 = *(const short8*)&sm.HsP[kt2][mf * 16 + (lane & 15)][8 * (lane >> 4)];
            acc2[mf] = __builtin_amdgcn_mfma_f32_16x16x32_bf16(af2, bf2, acc2[mf], 0, 0, 0);
        }
    }

    const int oc = wv * 16 + (lane & 15);
    const float bo = b2[oc];
#pragma unroll
    for (int mf = 0; mf < 4; ++mf) {
#pragma unroll
        for (int r = 0; r < 4; ++r) {
            long long row = (long long)bm0 + mf * 16 + 4 * (lane >> 4) + r;
            if (row < n) {
                float v = acc2[mf][r] + bo;
                ax0[row * 64 + oc] = f2bf(0.1f * v);
                zs0[row * 64 + oc] = f2bf(dinv[row] * v);
            }
        }
    }
}

// ---------------------------------------------------------------- propagation
// zs = bf16(dinv*z), layout [node][64]. Wave = node.
// lane = (edge-slot lane>>3) x (channel-group lane&7, 8 channels = 16 B).
// One uint4 gather covers 8 edges/instruction (each 8-lane group reads one
// full 128-B row, coalesced). rec read as coalesced vector load.
// LAST=1 fuses log_softmax, writes fp32 out.
template<int LAST>
__global__ __launch_bounds__(256) void k_prop(const unsigned short* __restrict__ zs,
        const unsigned short* __restrict__ ax0, const int* __restrict__ rowptr,
        const int* __restrict__ rec, const float* __restrict__ dinv,
        unsigned short* __restrict__ zso, float* __restrict__ zfout, int n) {
    int node = __builtin_amdgcn_readfirstlane(blockIdx.x * 4 + (threadIdx.x >> 6));
    if (node >= n) return;
    const int lane = threadIdx.x & 63;
    const int slot = lane >> 3;        // 8 edge slots
    const int cgb  = (lane & 7) * 16;  // channel-group byte offset within row
    const char* zb = (const char*)zs;
    const int e0 = rowptr[node], e1 = rowptr[node + 1];

    f32x4 aA = {0.f, 0.f, 0.f, 0.f};   // even channels (lo halves)
    f32x4 aB = {0.f, 0.f, 0.f, 0.f};   // odd channels (hi halves)

    int e = e0;
    for (; e + 8 <= e1; e += 8) {
        int r = rec[e + slot];
        uint4 d = *(const uint4*)(zb + (size_t)r + cgb);
        aA.x += ulo(d.x); aB.x += uhi(d.x);
        aA.y += ulo(d.y); aB.y += uhi(d.y);
        aA.z += ulo(d.z); aB.z += uhi(d.z);
        aA.w += ulo(d.w); aB.w += uhi(d.w);
    }
    if (e < e1) {                       // tail: mask lanes past the end
        int ei = e + slot;
        int ec = (ei < e1) ? ei : (e1 - 1);
        int r = rec[ec];
        uint4 d = *(const uint4*)(zb + (size_t)r + cgb);
        float w = (ei < e1) ? 1.f : 0.f;
        aA.x = fmaf(w, ulo(d.x), aA.x); aB.x = fmaf(w, uhi(d.x), aB.x);
        aA.y = fmaf(w, ulo(d.y), aA.y); aB.y = fmaf(w, uhi(d.y), aB.y);
        aA.z = fmaf(w, ulo(d.z), aA.z); aB.z = fmaf(w, uhi(d.z), aB.z);
        aA.w = fmaf(w, ulo(d.w), aA.w); aB.w = fmaf(w, uhi(d.w), aB.w);
    }

    // reduce across the 8 slots (lane bits 3..5)
#pragma unroll
    for (int o = 8; o <= 32; o <<= 1) {
        aA.x += __shfl_xor(aA.x, o, 64);
        aA.y += __shfl_xor(aA.y, o, 64);
        aA.z += __shfl_xor(aA.z, o, 64);
        aA.w += __shfl_xor(aA.w, o, 64);
        aB.x += __shfl_xor(aB.x, o, 64);
        aB.y += __shfl_xor(aB.y, o, 64);
        aB.z += __shfl_xor(aB.z, o, 64);
        aB.w += __shfl_xor(aB.w, o, 64);
    }

    // self loop
    uint4 ds = *(const uint4*)(zb + (size_t)node * 128 + cgb);
    aA.x += ulo(ds.x); aB.x += uhi(ds.x);
    aA.y += ulo(ds.y); aB.y += uhi(ds.y);
    aA.z += ulo(ds.z); aB.z += uhi(ds.z);
    aA.w += ulo(ds.w); aB.w += uhi(ds.w);

    const float dv = dinv[node];
    uint4 da = *(const uint4*)((const char*)ax0 + (size_t)node * 128 + cgb);
    float z0 = 0.9f * (dv * aA.x) + ulo(da.x);
    float z1 = 0.9f * (dv * aB.x) + uhi(da.x);
    float z2 = 0.9f * (dv * aA.y) + ulo(da.y);
    float z3 = 0.9f * (dv * aB.y) + uhi(da.y);
    float z4 = 0.9f * (dv * aA.z) + ulo(da.z);
    float z5 = 0.9f * (dv * aB.z) + uhi(da.z);
    float z6 = 0.9f * (dv * aA.w) + ulo(da.w);
    float z7 = 0.9f * (dv * aB.w) + uhi(da.w);

    if (LAST) {
        float m = fmaxf(fmaxf(fmaxf(z0, z1), fmaxf(z2, z3)),
                        fmaxf(fmaxf(z4, z5), fmaxf(z6, z7)));
        m = fmaxf(m, __shfl_xor(m, 1, 64));
        m = fmaxf(m, __shfl_xor(m, 2, 64));
        m = fmaxf(m, __shfl_xor(m, 4, 64));
        float s = expf(z0 - m) + expf(z1 - m) + expf(z2 - m) + expf(z3 - m)
                + expf(z4 - m) + expf(z5 - m) + expf(z6 - m) + expf(z7 - m);
        s += __shfl_xor(s, 1, 64);
        s += __shfl_xor(s, 2, 64);
        s += __shfl_xor(s, 4, 64);
        float ls = m + logf(s);
        if (slot == 0) {
            float4 o0 = {z0 - ls, z1 - ls, z2 - ls, z3 - ls};
            float4 o1 = {z4 - ls, z5 - ls, z6 - ls, z7 - ls};
            *(float4*)(zfout + (size_t)node * 64 + (lane & 7) * 8) = o0;
            *(float4*)(zfout + (size_t)node * 64 + (lane & 7) * 8 + 4) = o1;
        }
    } else {
        if (slot == 0) {
            uint4 pk;
            pk.x = (unsigned int)f2bf(dv * z0) | ((unsigned int)f2bf(dv * z1) << 16);
            pk.y = (unsigned int)f2bf(dv * z2) | ((unsigned int)f2bf(dv * z3) << 16);
            pk.z = (unsigned int)f2bf(dv * z4) | ((unsigned int)f2bf(dv * z5) << 16);
            pk.w = (unsigned int)f2bf(dv * z6) | ((unsigned int)f2bf(dv * z7) << 16);
            *(uint4*)((char*)zso + (size_t)node * 128 + cgb) = pk;
        }
    }
}

// ---------------------------------------------------------------- launch
extern "C" void kernel_launch(void* const* d_in, const int* in_sizes, int n_in,
                              void* d_out, int out_size, void* d_ws, size_t ws_size,
                              hipStream_t stream) {
    const float* x  = (const float*)d_in[0];
    const void*  ei = d_in[1];
    const float* W1 = (const float*)d_in[2];
    const float* b1 = (const float*)d_in[3];
    const float* W2 = (const float*)d_in[4];
    const float* b2 = (const float*)d_in[5];
    float* out = (float*)d_out;

    const int n = in_sizes[0] / 512;
    const int E = in_sizes[1] / 2;
    const int NB = (n + 255) >> 8;

    char* p = (char*)d_ws;
    auto alloc = [&](size_t bytes) {
        void* r = (void*)p;
        p += (bytes + 255) & ~(size_t)255;
        return r;
    };
    int*   rowptr  = (int*)alloc((size_t)(n + 1) * 4);
    int*   flag    = (int*)alloc(4);
    int*   bktcnt  = (int*)alloc(NBKT * 4);
    int*   bktbase = (int*)alloc((NBKT + 1) * 4);
    int*   bcur    = (int*)alloc(NBKT * 4);
    float* dinv    = (float*)alloc((size_t)n * 4);
    int*   rec     = (int*)alloc((size_t)E * 4);
    unsigned int* ebuf = (unsigned int*)alloc((size_t)E * 4);
    unsigned short* ax0 = (unsigned short*)alloc((size_t)n * 64 * 2);
    unsigned short* zsA = (unsigned short*)alloc((size_t)n * 64 * 2);
    unsigned short* zsB = (unsigned short*)alloc((size_t)n * 64 * 2);
    unsigned short* W1f = (unsigned short*)alloc(65536 * 2);
    unsigned short* W2f = (unsigned short*)alloc(8192 * 2);

    k_init<<<2, 256, 0, stream>>>(bktcnt, flag);
    k_detect<<<2, 256, 0, stream>>>((const int*)ei, E, flag);
    k_wprep<<<(65536 + 8192 + 255) / 256, 256, 0, stream>>>(W1, W2, W1f, W2f);
    k_bhist<<<512, 256, 0, stream>>>(ei, E, flag, bktcnt, n);
    k_bscan<<<1, 512, 0, stream>>>(bktcnt, bktbase, bcur, n);
    k_bucketA<<<512, 256, 0, stream>>>(ei, E, flag, bcur, ebuf, n);
    k_bucketB<<<NB, 256, 0, stream>>>(ebuf, bktbase, rowptr, rec, dinv, n);
    k_mlp<<<(n + 63) / 64, 256, 0, stream>>>(x, W1f, b1, W2f, b2, dinv, ax0, zsA, n);

    const unsigned short* zi = zsA;
    unsigned short* zo = zsB;
    for (int it = 0; it < KITER - 1; ++it) {
        k_prop<0><<<(n + 3) / 4, 256, 0, stream>>>(zi, ax0, rowptr, rec, dinv, zo, nullptr, n);
        const unsigned short* t = zi; zi = zo; zo = (unsigned short*)t;
    }
    k_prop<1><<<(n + 3) / 4, 256, 0, stream>>>(zi, ax0, rowptr, rec, dinv, nullptr, out, n);
}